// Round 5
// baseline (218.416 us; speedup 1.0000x reference)
//
#include <hip/hip_runtime.h>

// PlateYoloBlock: (32,13,256,256) fp32 -> (32,65536,13) fp32
// out[b][y*256+x][c]:
//   c=0: (sigmoid(v)+x)*8   c=1: (sigmoid(v)+y)*8
//   c=2,3: exp(v)*8         c=4..11: v*8          c=12: sigmoid(v)
//
// v4 (resubmit; prior round was an infra failure, kernel never ran):
// NO LDS, NO BARRIER. v1/v2/v3b all tied at 66us with ~equal
// bytes-in-flight per CU and the same stage->barrier->store convoy;
// hypothesis: effective-latency/queuing bound. v4 raises in-flight bytes
// (13x dwordx4 per wave AND ~16 waves/CU, VGPR-capped instead of
// LDS-capped) and removes the phase structure entirely.
// Each thread: 4 consecutive positions -> 13 global_load_dwordx4 (all
// independent), register math, then 13 global_store_dwordx4 into its own
// CONTIGUOUS 208B output region (52 floats = 4 positions x 13 attrs).
// Store lanes scatter at 208B stride, but each 128B line is fully
// written by one wave in one burst -> L2 merges, no write amplification.

#define NB      32
#define NC      13
#define HW      65536     // 256*256 positions per batch
#define WIDTH   256
#define THREADS 256
#define PPT     4         // positions per thread
#define TILE    (THREADS * PPT)          // 1024 positions per block
#define NBLOCKS ((NB * HW) / TILE)       // 2048

typedef float v4f __attribute__((ext_vector_type(4)));

__device__ __forceinline__ float sigmoidf_(float x) {
    return 1.0f / (1.0f + __expf(-x));
}

__global__ __launch_bounds__(THREADS) void plate_yolo_kernel(
        const float* __restrict__ in, float* __restrict__ out) {
    const int tid = threadIdx.x;
    const long long s0 = (long long)blockIdx.x * TILE;   // global spatial base
    const int b = (int)(s0 >> 16);                       // 65536 positions/batch
    const int posBase = (int)(s0 & (HW - 1));
    const float* __restrict__ inB = in + (long long)b * NC * HW + posBase;

    const int p0   = tid * PPT;         // 4 consecutive positions, mult of 4
    const int pos0 = posBase + p0;
    const float fx0 = (float)(pos0 & (WIDTH - 1));  // row not crossed in a quad
    const float fy  = (float)(pos0 >> 8);

    // Phase A: 13 independent float4 loads, all issued before any use.
    // 13 KB in flight per wave; no LDS -> occupancy VGPR-capped (~16 waves/CU).
    v4f v[NC];
    #pragma unroll
    for (int c = 0; c < NC; ++c) {
        v[c] = *(const v4f*)(inB + c * HW + p0);
    }

    // Phase B: pointwise math into output-layout register block.
    float res[PPT * NC];                 // res[q*13 + c], all static indices
    #pragma unroll
    for (int c = 0; c < NC; ++c) {
        #pragma unroll
        for (int q = 0; q < PPT; ++q) {
            const float x = v[c][q];
            float r;
            if (c == 0)                 r = (sigmoidf_(x) + (fx0 + (float)q)) * 8.0f;
            else if (c == 1)            r = (sigmoidf_(x) + fy) * 8.0f;
            else if (c == 2 || c == 3)  r = __expf(x) * 8.0f;
            else if (c == 12)           r = sigmoidf_(x);
            else                        r = x * 8.0f;
            res[q * NC + c] = r;
        }
    }

    // Phase C: 13 dwordx4 stores into the thread's contiguous 52-float
    // output region. Byte base = (s0+p0)*52 -> multiple of 208 -> 16B-aligned.
    v4f* __restrict__ dst = (v4f*)(out + (s0 + p0) * NC);
    #pragma unroll
    for (int j = 0; j < NC; ++j) {
        v4f w;
        w[0] = res[4*j + 0]; w[1] = res[4*j + 1];
        w[2] = res[4*j + 2]; w[3] = res[4*j + 3];
        dst[j] = w;
    }
}

extern "C" void kernel_launch(void* const* d_in, const int* in_sizes, int n_in,
                              void* d_out, int out_size, void* d_ws, size_t ws_size,
                              hipStream_t stream) {
    const float* in = (const float*)d_in[0];
    float* out = (float*)d_out;
    plate_yolo_kernel<<<NBLOCKS, THREADS, 0, stream>>>(in, out);
}

// Round 6
// 193.709 us; speedup vs baseline: 1.1275x; 1.1275x over previous
//
#include <hip/hip_runtime.h>

// PlateYoloBlock: (32,13,256,256) fp32 -> (32,65536,13) fp32
// out[b][y*256+x][c]:
//   c=0: (sigmoid(v)+x)*8   c=1: (sigmoid(v)+y)*8
//   c=2,3: exp(v)*8         c=4..11: v*8          c=12: sigmoid(v)
//
// v5: kill the barrier-drain convoy. Every 66us variant used
// __syncthreads(), which compiles to s_waitcnt vmcnt(0)+s_barrier — the
// read pipe drains to EMPTY once per tile, so reads and writes alternate
// in bursts and neither stream runs continuously. v5 register-stages a
// double-buffered sub-tile pipeline with RAW s_barrier + lgkmcnt-only
// waits: vmcnt is NEVER drained inside the loop; tile t+1's 7 dwordx4
// loads are issued BEFORE tile t's math (T14 async-split, pinned by
// sched_barrier(0)) and stay outstanding across both barriers.
// Stores remain fully coalesced via the proven LDS transpose (v1 bank
// pattern: lane stride 52 floats -> 2-way/bank = free; no write-amp).

#define NB      32
#define NC      13
#define HW      65536     // 256*256 positions per batch
#define WIDTH   256
#define THREADS 256
#define SUB     512                    // positions per sub-tile
#define NT      4                      // sub-tiles per block (pipelined)
#define TILE    (SUB * NT)             // 2048 positions per block
#define NBLOCKS ((NB * HW) / TILE)     // 1024 -> 4 blocks/CU
#define NSLOT   (SUB * NC / 4)         // 1664 float4 slots per sub-tile

typedef float v4f __attribute__((ext_vector_type(4)));

__device__ __forceinline__ float sigmoidf_(float x) {
    return 1.0f / (1.0f + __expf(-x));
}

__global__ __launch_bounds__(THREADS) void plate_yolo_kernel(
        const float* __restrict__ in, float* __restrict__ out) {
    __shared__ float lds[SUB * NC];    // 26,624 B (single buffer, reused per sub-tile)

    const int tid = threadIdx.x;
    const long long s0 = (long long)blockIdx.x * TILE;   // global spatial base
    const int b = (int)(s0 >> 16);                       // tile never crosses a batch
    const int posBase = (int)(s0 & (HW - 1));
    const float* __restrict__ inB = in + (long long)b * NC * HW + posBase;

    // Slot map: slot s (0..1663) = channel c = s>>7, 4 floats at (s&127)*4.
    // s = tid + k*256: consecutive tid -> consecutive 16B -> coalesced.
    // k=6 covers s=1536..1663: waves 0,1 fully active, waves 2,3 fully idle
    // (wave-uniform predicate, no intra-wave divergence).
    v4f vA[7], vB[7];

    auto load_tile = [&](int t, v4f* dst) {
        const float* base = inB + t * SUB;
        #pragma unroll
        for (int k = 0; k < 7; ++k) {
            const int s = tid + k * THREADS;
            if (s < NSLOT)
                dst[k] = *(const v4f*)(base + (s >> 7) * HW + ((s & 127) << 2));
        }
    };

    load_tile(0, vA);

    #pragma unroll
    for (int t = 0; t < NT; ++t) {
        v4f* cur = (t & 1) ? vB : vA;   // static after full unroll (rule #20 safe)
        v4f* nxt = (t & 1) ? vA : vB;

        // Prefetch next sub-tile FIRST; sched_barrier pins the issue point so
        // the loads sit in the VMEM queue under all of tile t's work.
        if (t + 1 < NT) load_tile(t + 1, nxt);
        __builtin_amdgcn_sched_barrier(0);

        // Math + LDS transpose-write for tile t (compiler emits counted
        // vmcnt before first use of cur; nxt's loads stay outstanding).
        #pragma unroll
        for (int k = 0; k < 7; ++k) {
            const int s = tid + k * THREADS;
            if (s < NSLOT) {
                const int c  = s >> 7;          // wave-uniform
                const int pl = (s & 127) << 2;  // local position base
                #pragma unroll
                for (int q = 0; q < 4; ++q) {
                    const float x = cur[k][q];
                    const int p = pl + q;
                    float r;
                    if (c == 0) {
                        const int pos = posBase + t * SUB + p;
                        r = (sigmoidf_(x) + (float)(pos & (WIDTH - 1))) * 8.0f;
                    } else if (c == 1) {
                        const int pos = posBase + t * SUB + p;
                        r = (sigmoidf_(x) + (float)(pos >> 8)) * 8.0f;
                    } else if (c == 2 || c == 3) {
                        r = __expf(x) * 8.0f;
                    } else if (c == 12) {
                        r = sigmoidf_(x);
                    } else {
                        r = x * 8.0f;
                    }
                    lds[p * NC + c] = r;
                }
            }
        }

        // Raw barrier with lgkmcnt-only wait: ds_writes visible to all waves,
        // but global loads (vmcnt) remain in flight — no read-pipe drain.
        asm volatile("s_waitcnt lgkmcnt(0)" ::: "memory");
        __builtin_amdgcn_s_barrier();

        // Coalesced float4 copy-out of tile t (ds_read_b128 + store_dwordx4).
        {
            const v4f* __restrict__ src4 = (const v4f*)lds;
            v4f* __restrict__ dst4 = (v4f*)(out + (s0 + t * SUB) * NC);
            #pragma unroll
            for (int k = 0; k < 7; ++k) {
                const int s = tid + k * THREADS;
                if (s < NSLOT) dst4[s] = src4[s];
            }
        }

        // ds_reads retired before next tile's ds_writes may overwrite.
        asm volatile("s_waitcnt lgkmcnt(0)" ::: "memory");
        __builtin_amdgcn_s_barrier();
    }
}

extern "C" void kernel_launch(void* const* d_in, const int* in_sizes, int n_in,
                              void* d_out, int out_size, void* d_ws, size_t ws_size,
                              hipStream_t stream) {
    const float* in = (const float*)d_in[0];
    float* out = (float*)d_out;
    plate_yolo_kernel<<<NBLOCKS, THREADS, 0, stream>>>(in, out);
}

// Round 7
// 190.105 us; speedup vs baseline: 1.1489x; 1.0190x over previous
//
#include <hip/hip_runtime.h>

// PlateYoloBlock: (32,13,256,256) fp32 -> (32,65536,13) fp32
// out[b][y*256+x][c]:
//   c=0: (sigmoid(v)+x)*8   c=1: (sigmoid(v)+y)*8
//   c=2,3: exp(v)*8         c=4..11: v*8          c=12: sigmoid(v)
//
// v6: change the READ MACHINERY, nothing else. All VGPR-return variants
// (scalar, dwordx4, any occupancy, nt, swizzle, pipelined) pin reads at
// ~1.7 TB/s while write-only fill does 6.6 TB/s -> hypothesis: the CU's
// vector-return path (L1 miss tracking / return queue) caps outstanding
// read lines. global_load_lds is the one read path that bypasses the
// VGPR return: 26x 1KB DMA units -> raw-layout LDS bufA, then the proven
// v1 transform (2-way-free banking) into bufB, then the proven coalesced
// float4 copy-out. Single variable changed vs v1.

#define NB      32
#define NC      13
#define HW      65536     // 256*256 positions per batch
#define WIDTH   256
#define TILE    512       // positions per block
#define THREADS 256
#define NBLOCKS ((NB * HW) / TILE)   // 4096

typedef float v4f __attribute__((ext_vector_type(4)));

__device__ __forceinline__ float sigmoidf_(float x) {
    return 1.0f / (1.0f + __expf(-x));
}

__global__ __launch_bounds__(THREADS) void plate_yolo_kernel(
        const float* __restrict__ in, float* __restrict__ out) {
    __shared__ float bufA[NC * TILE];   // raw input, channel-major: bufA[c*512+p]
    __shared__ float bufB[TILE * NC];   // output layout: bufB[p*13+c]
    // 2 x 26,624 B = 53,248 B -> 3 blocks/CU (12 waves/CU; occupancy is
    // a non-factor per v1/v2 insensitivity 24-49%).

    const int tid  = threadIdx.x;
    const int lane = tid & 63;
    const int wave = tid >> 6;

    const long long s0 = (long long)blockIdx.x * TILE;   // global spatial base
    const int b = (int)(s0 >> 16);                       // tile within one batch
    const int posBase = (int)(s0 & (HW - 1));
    const float* __restrict__ inB = in + (long long)b * NC * HW + posBase;

    // Stage 1: 26 DMA units of 1 KB (13 channels x 2 halves) direct to LDS.
    // Unit u: global = inB + (u>>1)*HW + (u&1)*256 floats, lane covers 16B.
    // LDS dest is wave-uniform base + lane*16 -> bufA[u*256] linear. No VGPR
    // destination -> read returns bypass the vector return queue.
    #pragma unroll
    for (int k = 0; k < 7; ++k) {
        const int u = wave * 7 + k;          // waves 0-2: 7 units, wave 3: 5
        if (u < 26) {                        // wave-uniform predicate
            const int c    = u >> 1;
            const int half = u & 1;
            const float* g = inB + c * HW + half * 256 + lane * 4;
            __builtin_amdgcn_global_load_lds(
                (const __attribute__((address_space(1))) void*)g,
                (__attribute__((address_space(3))) void*)&bufA[u * 256],
                16, 0, 0);
        }
    }
    __syncthreads();   // vmcnt(0)+lgkmcnt(0)+barrier: bufA complete

    // Stage 2: v1's proven transform indexing. Reads bufA[c*512 + tid+k*256]
    // (lane stride 1 dword -> conflict-free); writes bufB[p*13+c] (lane
    // stride 13 dwords, gcd(13,32)=1 -> 2-way = free).
    #pragma unroll
    for (int k = 0; k < TILE / THREADS; ++k) {
        const int p = tid + k * THREADS;
        const int pos = posBase + p;
        const float fx = (float)(pos & (WIDTH - 1));
        const float fy = (float)(pos >> 8);
        #pragma unroll
        for (int c = 0; c < NC; ++c) {
            const float x = bufA[c * TILE + p];
            float r;
            if (c == 0)                 r = (sigmoidf_(x) + fx) * 8.0f;
            else if (c == 1)            r = (sigmoidf_(x) + fy) * 8.0f;
            else if (c == 2 || c == 3)  r = __expf(x) * 8.0f;
            else if (c == 12)           r = sigmoidf_(x);
            else                        r = x * 8.0f;
            bufB[p * NC + c] = r;
        }
    }
    __syncthreads();

    // Stage 3: proven coalesced float4 copy-out (ds_read_b128 +
    // global_store_dwordx4). Tile base byte offset multiple of 16.
    const v4f* __restrict__ src = (const v4f*)bufB;
    v4f* __restrict__ dst = (v4f*)(out + s0 * NC);
    const int n4 = TILE * NC / 4;   // 1664
    #pragma unroll
    for (int j = tid; j < n4; j += THREADS) {
        dst[j] = src[j];
    }
}

extern "C" void kernel_launch(void* const* d_in, const int* in_sizes, int n_in,
                              void* d_out, int out_size, void* d_ws, size_t ws_size,
                              hipStream_t stream) {
    const float* in = (const float*)d_in[0];
    float* out = (float*)d_out;
    plate_yolo_kernel<<<NBLOCKS, THREADS, 0, stream>>>(in, out);
}